// Round 2
// baseline (290.094 us; speedup 1.0000x reference)
//
#include <hip/hip_runtime.h>
#include <stdint.h>

#define BSZ 8
#define GQ 2000
#define NPTS (BSZ * GQ)
#define CH 128            // C_IN == C_OUT == 128
#define KOFF 125          // 5^3 offsets
#define KSELF 62          // (0,0,0) offset index
#define TBL_BITS 16
#define TBL_SIZE (1 << TBL_BITS)
#define TBL_MASK (TBL_SIZE - 1)
#define OTHER_CAP 16384
#define TM 32             // rows per gemm62 block

// ---- workspace layout (bytes) ----
// 0        : hash table   Slot[65536]        (512 KB)  memset 0xFF
// 524288   : counters     int[2] {cnt62, cntOther}      memset 0
// 524544   : pairs62      int2[NPTS]         (128 KB)
// 652544   : pairsOther   int4[OTHER_CAP]    (256 KB)
// 914688   : voxbuf       int4[NPTS]         (250 KB)  {vx,vy,vz,b}
#define WS_CNT_OFF   524288
#define WS_P62_OFF   524544
#define WS_POTH_OFF  652544
#define WS_VOX_OFF   914688

struct Slot { int key; int val; };

__device__ __forceinline__ uint32_t hash_of(uint32_t k) {
    return (k * 2654435761u) >> (32 - TBL_BITS);
}

// Exact replication of the reference's fp32 voxel-index arithmetic
__device__ __forceinline__ int3 voxel_idx(const float* __restrict__ anchor, int i,
                                          float sx, float sy, float sz,
                                          float lx, float ly, float lz, float g) {
    float ax = anchor[i * 3 + 0];
    float ay = anchor[i * 3 + 1];
    float az = anchor[i * 3 + 2];
    float x = __fadd_rn(__fmul_rn(ax, sx), lx);
    float y = __fadd_rn(__fmul_rn(ay, sy), ly);
    float z = __fadd_rn(__fmul_rn(az, sz), lz);
    int ix = (int)__fdiv_rn(__fsub_rn(x, lx), g);
    int iy = (int)__fdiv_rn(__fsub_rn(y, ly), g);
    int iz = (int)__fdiv_rn(__fsub_rn(z, lz), g);
    return make_int3(ix, iy, iz);
}

__global__ void build_hash_kernel(const float* __restrict__ anchor,
                                  Slot* __restrict__ tab,
                                  int4* __restrict__ voxbuf,
                                  float sx, float sy, float sz,
                                  float lx, float ly, float lz, float g,
                                  int Dx, int Dy, int Dz) {
    int i = blockIdx.x * blockDim.x + threadIdx.x;
    if (i >= NPTS) return;
    int3 v = voxel_idx(anchor, i, sx, sy, sz, lx, ly, lz, g);
    int b = i / GQ;
    voxbuf[i] = make_int4(v.x, v.y, v.z, b);
    // OOB scatter updates are dropped (JAX default scatter mode)
    if (v.x < 0 || v.x >= Dx || v.y < 0 || v.y >= Dy || v.z < 0 || v.z >= Dz) return;
    int key = ((b * Dx + v.x) * Dy + v.y) * Dz + v.z;
    uint32_t slot = hash_of((uint32_t)key);
    for (;;) {
        int prev = atomicCAS(&tab[slot].key, -1, key);
        if (prev == -1 || prev == key) {
            atomicMax(&tab[slot].val, i);   // duplicate voxel: max index wins (last write)
            break;
        }
        slot = (slot + 1) & TBL_MASK;
    }
}

__device__ __forceinline__ int hash_query(const Slot* __restrict__ tab, int key) {
    uint32_t slot = hash_of((uint32_t)key);
    for (;;) {
        int k = tab[slot].key;
        if (k == key) return tab[slot].val;
        if (k == -1) return -1;
        slot = (slot + 1) & TBL_MASK;
    }
}

// One thread per (point, offset). Valid taps go to pairs62 (k==62) or pairsOther.
__global__ void pairgen_kernel(const int4* __restrict__ voxbuf,
                               const Slot* __restrict__ tab,
                               int* __restrict__ counters,
                               int2* __restrict__ pairs62,
                               int4* __restrict__ pairsOther,
                               int Dx, int Dy, int Dz) {
    int tid = blockIdx.x * blockDim.x + threadIdx.x;
    if (tid >= NPTS * KOFF) return;
    int i = tid / KOFF;
    int k = tid - i * KOFF;
    int4 v = voxbuf[i];
    int ox = k / 25 - 2;
    int oy = (k / 5) % 5 - 2;
    int oz = k % 5 - 2;
    int nx = v.x + ox, ny = v.y + oy, nz = v.z + oz;
    if (nx < 0 || nx >= Dx || ny < 0 || ny >= Dy || nz < 0 || nz >= Dz) return;
    int key = ((v.w * Dx + nx) * Dy + ny) * Dz + nz;
    int j = hash_query(tab, key);
    if (j < 0) return;
    if (k == KSELF) {
        int p = atomicAdd(&counters[0], 1);
        pairs62[p] = make_int2(i, j);
    } else {
        int p = atomicAdd(&counters[1], 1);
        if (p < OTHER_CAP) pairsOther[p] = make_int4(i, j, k, 0);
    }
}

// Batched GEMM for the self-offset group: out[i] = feats[j] @ w[62].
// Block: 256 threads, 32 rows x 128 cols, 4x4 register tile per thread.
__global__ void __launch_bounds__(256)
gemm62_kernel(const float* __restrict__ feat,
              const float* __restrict__ w,       // full (125,128,128)
              const int2* __restrict__ pairs62,
              const int* __restrict__ counters,
              float* __restrict__ out) {
    __shared__ float As[TM * CH];   // 16 KB, row-major [row][k]
    __shared__ int rowi[TM];

    int n = counters[0];
    int rowbase = blockIdx.x * TM;
    int t = threadIdx.x;

    // stage A: 32 rows x 32 float4
    for (int f = t; f < TM * 32; f += 256) {
        int r = f >> 5;
        int c4 = f & 31;
        int row = rowbase + r;
        float4 val = make_float4(0.f, 0.f, 0.f, 0.f);
        if (row < n) {
            int2 pr = pairs62[row];
            if (c4 == 0) rowi[r] = pr.x;
            val = *(const float4*)(feat + (size_t)pr.y * CH + c4 * 4);
        } else if (c4 == 0) {
            rowi[r] = -1;
        }
        *(float4*)(As + r * CH + c4 * 4) = val;
    }
    __syncthreads();

    int tc = t & 31;        // col group: cols tc*4 .. tc*4+3
    int tr = t >> 5;        // row group: rows tr*4 .. tr*4+3
    int r0 = tr * 4;

    float acc[4][4];
    #pragma unroll
    for (int a = 0; a < 4; ++a)
        #pragma unroll
        for (int b = 0; b < 4; ++b) acc[a][b] = 0.f;

    const float* B = w + (size_t)KSELF * CH * CH + tc * 4;
    #pragma unroll 4
    for (int k = 0; k < CH; ++k) {
        float4 b4 = *(const float4*)(B + (size_t)k * CH);
        float a0 = As[(r0 + 0) * CH + k];
        float a1 = As[(r0 + 1) * CH + k];
        float a2 = As[(r0 + 2) * CH + k];
        float a3 = As[(r0 + 3) * CH + k];
        acc[0][0] = fmaf(a0, b4.x, acc[0][0]); acc[0][1] = fmaf(a0, b4.y, acc[0][1]);
        acc[0][2] = fmaf(a0, b4.z, acc[0][2]); acc[0][3] = fmaf(a0, b4.w, acc[0][3]);
        acc[1][0] = fmaf(a1, b4.x, acc[1][0]); acc[1][1] = fmaf(a1, b4.y, acc[1][1]);
        acc[1][2] = fmaf(a1, b4.z, acc[1][2]); acc[1][3] = fmaf(a1, b4.w, acc[1][3]);
        acc[2][0] = fmaf(a2, b4.x, acc[2][0]); acc[2][1] = fmaf(a2, b4.y, acc[2][1]);
        acc[2][2] = fmaf(a2, b4.z, acc[2][2]); acc[2][3] = fmaf(a2, b4.w, acc[2][3]);
        acc[3][0] = fmaf(a3, b4.x, acc[3][0]); acc[3][1] = fmaf(a3, b4.y, acc[3][1]);
        acc[3][2] = fmaf(a3, b4.z, acc[3][2]); acc[3][3] = fmaf(a3, b4.w, acc[3][3]);
    }

    #pragma unroll
    for (int rr = 0; rr < 4; ++rr) {
        int i = rowi[r0 + rr];
        if (i >= 0) {
            float4 v = make_float4(acc[rr][0], acc[rr][1], acc[rr][2], acc[rr][3]);
            *(float4*)(out + (size_t)i * CH + tc * 4) = v;
        }
    }
}

// Remaining (non-self) taps: one pair per block iteration, atomicAdd into out.
__global__ void __launch_bounds__(CH)
scatter_other_kernel(const float* __restrict__ feat,
                     const float* __restrict__ w,
                     const int4* __restrict__ pairsOther,
                     const int* __restrict__ counters,
                     float* __restrict__ out) {
    __shared__ float fbuf[CH];
    int n = counters[1];
    if (n > OTHER_CAP) n = OTHER_CAP;
    int t = threadIdx.x;
    for (int p = blockIdx.x; p < n; p += gridDim.x) {
        int4 pr = pairsOther[p];
        __syncthreads();
        fbuf[t] = feat[(size_t)pr.y * CH + t];
        __syncthreads();
        const float* wk = w + (size_t)pr.z * CH * CH + t;
        float a0 = 0.f, a1 = 0.f, a2 = 0.f, a3 = 0.f;
        #pragma unroll 8
        for (int c = 0; c < CH; c += 4) {
            a0 = fmaf(fbuf[c + 0], wk[(c + 0) * CH], a0);
            a1 = fmaf(fbuf[c + 1], wk[(c + 1) * CH], a1);
            a2 = fmaf(fbuf[c + 2], wk[(c + 2) * CH], a2);
            a3 = fmaf(fbuf[c + 3], wk[(c + 3) * CH], a3);
        }
        atomicAdd(&out[(size_t)pr.x * CH + t], (a0 + a1) + (a2 + a3));
    }
}

extern "C" void kernel_launch(void* const* d_in, const int* in_sizes, int n_in,
                              void* d_out, int out_size, void* d_ws, size_t ws_size,
                              hipStream_t stream) {
    const float* feat   = (const float*)d_in[0];   // (8, 2000, 128)
    const float* anchor = (const float*)d_in[1];   // (8, 2000, 3)
    const float* w      = (const float*)d_in[2];   // (125, 128, 128)
    float* out = (float*)d_out;

    char* ws = (char*)d_ws;
    Slot* tab        = (Slot*)ws;
    int*  counters   = (int*)(ws + WS_CNT_OFF);
    int2* pairs62    = (int2*)(ws + WS_P62_OFF);
    int4* pairsOther = (int4*)(ws + WS_POTH_OFF);
    int4* voxbuf     = (int4*)(ws + WS_VOX_OFF);

    hipMemsetAsync(tab, 0xFF, (size_t)TBL_SIZE * sizeof(Slot), stream);
    hipMemsetAsync(counters, 0, 2 * sizeof(int), stream);
    hipMemsetAsync(out, 0, (size_t)out_size * sizeof(float), stream);

    // fp32 constants exactly as the reference computes them
    float lx = -20.0f, ly = -20.0f, lz = -2.3f;
    float hx =  20.0f, hy =  20.0f, hz =  0.9f;
    float sx = hx - lx, sy = hy - ly, sz = hz - lz;   // sz -> 3.1999998f
    float g = 0.1f;
    int Dx = (int)(sx / g);   // 400
    int Dy = (int)(sy / g);   // 400
    int Dz = (int)(sz / g);   // 31

    build_hash_kernel<<<(NPTS + 255) / 256, 256, 0, stream>>>(
        anchor, tab, voxbuf, sx, sy, sz, lx, ly, lz, g, Dx, Dy, Dz);

    pairgen_kernel<<<(NPTS * KOFF + 255) / 256, 256, 0, stream>>>(
        voxbuf, tab, counters, pairs62, pairsOther, Dx, Dy, Dz);

    gemm62_kernel<<<NPTS / TM, 256, 0, stream>>>(
        feat, w, pairs62, counters, out);

    scatter_other_kernel<<<1024, CH, 0, stream>>>(
        feat, w, pairsOther, counters, out);
}

// Round 3
// 112.125 us; speedup vs baseline: 2.5872x; 2.5872x over previous
//
#include <hip/hip_runtime.h>
#include <stdint.h>

#define BSZ 8
#define GQ 2000
#define NPTS (BSZ * GQ)
#define CH 128            // C_IN == C_OUT == 128
#define KOFF 125          // 5^3 offsets
#define KSELF 62          // (0,0,0) offset index
#define TBL_BITS 16
#define TBL_SIZE (1 << TBL_BITS)
#define TBL_MASK (TBL_SIZE - 1)
#define OTHER_CAP 16384
#define TM 32             // rows per gemm62 block
#define AS_LD 129         // LDS leading dim: 129 -> tr-groups land on distinct banks

// ---- workspace layout (bytes) ----
// 0        : hash table   Slot[65536]       (512 KB)  memset 0xFF
// 524288   : counters     int[1] {cntOther}  (cleared by build_hash)
// 524544   : pairs62      int[NPTS]          (64 KB)  j per point, -1 = none
// 589056   : pairsOther   int4[OTHER_CAP]    (256 KB)
// 851200   : voxbuf       int4[NPTS]         (256 KB) {vx,vy,vz,b}
#define WS_CNT_OFF   524288
#define WS_P62_OFF   524544
#define WS_POTH_OFF  589056
#define WS_VOX_OFF   851200

struct Slot { int key; int val; };

__device__ __forceinline__ uint32_t hash_of(uint32_t k) {
    return (k * 2654435761u) >> (32 - TBL_BITS);
}

// Exact replication of the reference's fp32 voxel-index arithmetic
__device__ __forceinline__ int3 voxel_idx(const float* __restrict__ anchor, int i,
                                          float sx, float sy, float sz,
                                          float lx, float ly, float lz, float g) {
    float ax = anchor[i * 3 + 0];
    float ay = anchor[i * 3 + 1];
    float az = anchor[i * 3 + 2];
    float x = __fadd_rn(__fmul_rn(ax, sx), lx);
    float y = __fadd_rn(__fmul_rn(ay, sy), ly);
    float z = __fadd_rn(__fmul_rn(az, sz), lz);
    int ix = (int)__fdiv_rn(__fsub_rn(x, lx), g);
    int iy = (int)__fdiv_rn(__fsub_rn(y, ly), g);
    int iz = (int)__fdiv_rn(__fsub_rn(z, lz), g);
    return make_int3(ix, iy, iz);
}

__global__ void build_hash_kernel(const float* __restrict__ anchor,
                                  Slot* __restrict__ tab,
                                  int4* __restrict__ voxbuf,
                                  int* __restrict__ counters,
                                  float sx, float sy, float sz,
                                  float lx, float ly, float lz, float g,
                                  int Dx, int Dy, int Dz) {
    int i = blockIdx.x * blockDim.x + threadIdx.x;
    if (i == 0) counters[0] = 0;          // cleared every call (ws is re-poisoned)
    if (i >= NPTS) return;
    int3 v = voxel_idx(anchor, i, sx, sy, sz, lx, ly, lz, g);
    int b = i / GQ;
    voxbuf[i] = make_int4(v.x, v.y, v.z, b);
    // OOB scatter updates are dropped (JAX default scatter mode)
    if (v.x < 0 || v.x >= Dx || v.y < 0 || v.y >= Dy || v.z < 0 || v.z >= Dz) return;
    int key = ((b * Dx + v.x) * Dy + v.y) * Dz + v.z;
    uint32_t slot = hash_of((uint32_t)key);
    for (;;) {
        int prev = atomicCAS(&tab[slot].key, -1, key);
        if (prev == -1 || prev == key) {
            atomicMax(&tab[slot].val, i);   // duplicate voxel: max index wins (last write)
            break;
        }
        slot = (slot + 1) & TBL_MASK;
    }
}

__device__ __forceinline__ int hash_query(const Slot* __restrict__ tab, int key) {
    uint32_t slot = hash_of((uint32_t)key);
    for (;;) {
        int k = tab[slot].key;
        if (k == key) return tab[slot].val;
        if (k == -1) return -1;
        slot = (slot + 1) & TBL_MASK;
    }
}

// One thread per (point, offset). Self-taps: direct-indexed store (no atomic).
// Other-taps: per-wave ballot aggregation -> one atomicAdd per hitting wave.
// No early returns: every lane reaches the ballot.
__global__ void pairgen_kernel(const int4* __restrict__ voxbuf,
                               const Slot* __restrict__ tab,
                               int* __restrict__ counters,
                               int* __restrict__ pairs62,
                               int4* __restrict__ pairsOther,
                               int Dx, int Dy, int Dz) {
    int tid = blockIdx.x * blockDim.x + threadIdx.x;
    bool inrange = tid < NPTS * KOFF;
    int ti = inrange ? tid : 0;
    int i = ti / KOFF;
    int k = ti - i * KOFF;
    int4 v = voxbuf[i];
    int ox = k / 25 - 2;
    int oy = (k / 5) % 5 - 2;
    int oz = k % 5 - 2;
    int nx = v.x + ox, ny = v.y + oy, nz = v.z + oz;
    bool inb = inrange && nx >= 0 && nx < Dx && ny >= 0 && ny < Dy && nz >= 0 && nz < Dz;
    int j = -1;
    if (inb) {
        int key = ((v.w * Dx + nx) * Dy + ny) * Dz + nz;
        j = hash_query(tab, key);
    }
    bool isself = inrange && (k == KSELF);
    if (isself) pairs62[i] = j;                 // -1 if no occupied self voxel
    bool hit = inrange && !isself && (j >= 0);
    unsigned long long mask = __ballot(hit);
    if (mask) {
        int lane = threadIdx.x & 63;
        int leader = __ffsll((unsigned long long)mask) - 1;
        int cnt = __popcll(mask);
        int base = 0;
        if (lane == leader) base = atomicAdd(&counters[0], cnt);
        base = __shfl(base, leader);
        if (hit) {
            int pos = base + (int)__popcll(mask & ((1ULL << lane) - 1ULL));
            if (pos < OTHER_CAP) pairsOther[pos] = make_int4(i, j, k, 0);
        }
    }
}

// Batched GEMM for the self-offset group: out[i] = feats[pairs62[i]] @ w[62]
// (zeros if pairs62[i] < 0). Covers ALL rows -> also serves as the out-init.
// Block: 256 threads, 32 rows x 128 cols, 4x4 register tile per thread.
__global__ void __launch_bounds__(256)
gemm62_kernel(const float* __restrict__ feat,
              const float* __restrict__ w,       // full (125,128,128)
              const int* __restrict__ pairs62,
              float* __restrict__ out) {
    __shared__ float As[TM * AS_LD];   // padded: bank(r0*AS_LD) distinct per tr

    int rowbase = blockIdx.x * TM;
    int t = threadIdx.x;

    // stage A: 32 rows x 32 float4-groups (scalar LDS stores due to odd stride)
    for (int f = t; f < TM * 32; f += 256) {
        int r = f >> 5;
        int c4 = f & 31;
        int j = pairs62[rowbase + r];
        float4 val = make_float4(0.f, 0.f, 0.f, 0.f);
        if (j >= 0) val = *(const float4*)(feat + (size_t)j * CH + c4 * 4);
        float* dst = As + r * AS_LD + c4 * 4;
        dst[0] = val.x; dst[1] = val.y; dst[2] = val.z; dst[3] = val.w;
    }
    __syncthreads();

    int tc = t & 31;        // col group: cols tc*4 .. tc*4+3
    int tr = t >> 5;        // row group: rows tr*4 .. tr*4+3
    int r0 = tr * 4;

    float acc[4][4];
    #pragma unroll
    for (int a = 0; a < 4; ++a)
        #pragma unroll
        for (int b = 0; b < 4; ++b) acc[a][b] = 0.f;

    const float* B = w + (size_t)KSELF * CH * CH + tc * 4;
    #pragma unroll 4
    for (int k = 0; k < CH; ++k) {
        float4 b4 = *(const float4*)(B + (size_t)k * CH);
        float a0 = As[(r0 + 0) * AS_LD + k];
        float a1 = As[(r0 + 1) * AS_LD + k];
        float a2 = As[(r0 + 2) * AS_LD + k];
        float a3 = As[(r0 + 3) * AS_LD + k];
        acc[0][0] = fmaf(a0, b4.x, acc[0][0]); acc[0][1] = fmaf(a0, b4.y, acc[0][1]);
        acc[0][2] = fmaf(a0, b4.z, acc[0][2]); acc[0][3] = fmaf(a0, b4.w, acc[0][3]);
        acc[1][0] = fmaf(a1, b4.x, acc[1][0]); acc[1][1] = fmaf(a1, b4.y, acc[1][1]);
        acc[1][2] = fmaf(a1, b4.z, acc[1][2]); acc[1][3] = fmaf(a1, b4.w, acc[1][3]);
        acc[2][0] = fmaf(a2, b4.x, acc[2][0]); acc[2][1] = fmaf(a2, b4.y, acc[2][1]);
        acc[2][2] = fmaf(a2, b4.z, acc[2][2]); acc[2][3] = fmaf(a2, b4.w, acc[2][3]);
        acc[3][0] = fmaf(a3, b4.x, acc[3][0]); acc[3][1] = fmaf(a3, b4.y, acc[3][1]);
        acc[3][2] = fmaf(a3, b4.z, acc[3][2]); acc[3][3] = fmaf(a3, b4.w, acc[3][3]);
    }

    #pragma unroll
    for (int rr = 0; rr < 4; ++rr) {
        int i = rowbase + r0 + rr;
        float4 v = make_float4(acc[rr][0], acc[rr][1], acc[rr][2], acc[rr][3]);
        *(float4*)(out + (size_t)i * CH + tc * 4) = v;   // unconditional: inits out
    }
}

// Remaining (non-self) taps: one pair per block iteration, atomicAdd into out.
__global__ void __launch_bounds__(CH)
scatter_other_kernel(const float* __restrict__ feat,
                     const float* __restrict__ w,
                     const int4* __restrict__ pairsOther,
                     const int* __restrict__ counters,
                     float* __restrict__ out) {
    __shared__ float fbuf[CH];
    int n = counters[0];
    if (n > OTHER_CAP) n = OTHER_CAP;
    int t = threadIdx.x;
    for (int p = blockIdx.x; p < n; p += gridDim.x) {
        int4 pr = pairsOther[p];
        __syncthreads();
        fbuf[t] = feat[(size_t)pr.y * CH + t];
        __syncthreads();
        const float* wk = w + (size_t)pr.z * CH * CH + t;
        float a0 = 0.f, a1 = 0.f, a2 = 0.f, a3 = 0.f;
        #pragma unroll 8
        for (int c = 0; c < CH; c += 4) {
            a0 = fmaf(fbuf[c + 0], wk[(c + 0) * CH], a0);
            a1 = fmaf(fbuf[c + 1], wk[(c + 1) * CH], a1);
            a2 = fmaf(fbuf[c + 2], wk[(c + 2) * CH], a2);
            a3 = fmaf(fbuf[c + 3], wk[(c + 3) * CH], a3);
        }
        atomicAdd(&out[(size_t)pr.x * CH + t], (a0 + a1) + (a2 + a3));
    }
}

extern "C" void kernel_launch(void* const* d_in, const int* in_sizes, int n_in,
                              void* d_out, int out_size, void* d_ws, size_t ws_size,
                              hipStream_t stream) {
    const float* feat   = (const float*)d_in[0];   // (8, 2000, 128)
    const float* anchor = (const float*)d_in[1];   // (8, 2000, 3)
    const float* w      = (const float*)d_in[2];   // (125, 128, 128)
    float* out = (float*)d_out;

    char* ws = (char*)d_ws;
    Slot* tab        = (Slot*)ws;
    int*  counters   = (int*)(ws + WS_CNT_OFF);
    int*  pairs62    = (int*)(ws + WS_P62_OFF);
    int4* pairsOther = (int4*)(ws + WS_POTH_OFF);
    int4* voxbuf     = (int4*)(ws + WS_VOX_OFF);

    hipMemsetAsync(tab, 0xFF, (size_t)TBL_SIZE * sizeof(Slot), stream);

    // fp32 constants exactly as the reference computes them
    float lx = -20.0f, ly = -20.0f, lz = -2.3f;
    float hx =  20.0f, hy =  20.0f, hz =  0.9f;
    float sx = hx - lx, sy = hy - ly, sz = hz - lz;   // sz -> 3.1999998f
    float g = 0.1f;
    int Dx = (int)(sx / g);   // 400
    int Dy = (int)(sy / g);   // 400
    int Dz = (int)(sz / g);   // 31

    build_hash_kernel<<<(NPTS + 255) / 256, 256, 0, stream>>>(
        anchor, tab, voxbuf, counters, sx, sy, sz, lx, ly, lz, g, Dx, Dy, Dz);

    pairgen_kernel<<<(NPTS * KOFF + 255) / 256, 256, 0, stream>>>(
        voxbuf, tab, counters, pairs62, pairsOther, Dx, Dy, Dz);

    gemm62_kernel<<<NPTS / TM, 256, 0, stream>>>(
        feat, w, pairs62, out);

    scatter_other_kernel<<<512, CH, 0, stream>>>(
        feat, w, pairsOther, counters, out);
}